// Round 1
// baseline (230.580 us; speedup 1.0000x reference)
//
#include <hip/hip_runtime.h>
#include <hip/hip_bf16.h>

typedef __bf16 bf16_t;
typedef __bf16 bf16x8 __attribute__((ext_vector_type(8)));
typedef float f32x4 __attribute__((ext_vector_type(4)));

#define LOG2E 1.44269504088896340736f

// ---------------- prep: W_eff = W + 2.0 * B @ A  (fold LoRA), cast bf16 ----
__global__ void prep_weff(const float* __restrict__ W,
                          const float* __restrict__ Bm,   // [O][8]
                          const float* __restrict__ Am,   // [8][1024]
                          bf16_t* __restrict__ Weff, int OC) {
  int idx = blockIdx.x * 256 + threadIdx.x;
  if (idx >= OC) return;
  int o = idx >> 10, c = idx & 1023;
  float acc = W[idx];
#pragma unroll
  for (int r = 0; r < 8; ++r)
    acc += 2.0f * Bm[o * 8 + r] * Am[r * 1024 + c];
  Weff[idx] = (bf16_t)acc;
}

__global__ void cast_bf(const float* __restrict__ X, bf16_t* __restrict__ Xb, int n) {
  int i = blockIdx.x * 256 + threadIdx.x;
  if (i < n) Xb[i] = (bf16_t)X[i];
}

// ---------------- GEMM: C[m][n] = sum_k A[m][k] * Bt[n][k] + bias[n] -------
// A [M][1024] bf16 row-major, Bt [N][1024] bf16 row-major.
// 128x128 tile, BK=64, 4 waves (2x2), each wave 64x64 via 4x4 mfma 16x16x32.
template <bool QKV>
__global__ __launch_bounds__(256) void gemm_bt(
    const bf16_t* __restrict__ A, const bf16_t* __restrict__ Bt,
    const float* __restrict__ bias,
    bf16_t* __restrict__ Qb, bf16_t* __restrict__ Kb, bf16_t* __restrict__ Vb,
    float* __restrict__ Out) {
  constexpr int Kdim = 1024;
  __shared__ bf16_t Als[128][72];
  __shared__ bf16_t Bls[128][72];
  const int m0 = blockIdx.x * 128;
  const int n0 = blockIdx.y * 128;
  const int tid = threadIdx.x;
  const int lane = tid & 63;
  const int w = tid >> 6;
  const int wm = w >> 1, wn = w & 1;
  const int lr = tid >> 1;            // staging row 0..127
  const int lc = (tid & 1) * 32;      // staging col chunk

  f32x4 acc[4][4] = {};

  for (int k0 = 0; k0 < Kdim; k0 += 64) {
    const bf16_t* pa = A + (size_t)(m0 + lr) * Kdim + k0 + lc;
    const bf16_t* pb = Bt + (size_t)(n0 + lr) * Kdim + k0 + lc;
#pragma unroll
    for (int u = 0; u < 4; ++u)
      *(int4*)&Als[lr][lc + u * 8] = *(const int4*)(pa + u * 8);
#pragma unroll
    for (int u = 0; u < 4; ++u)
      *(int4*)&Bls[lr][lc + u * 8] = *(const int4*)(pb + u * 8);
    __syncthreads();
#pragma unroll
    for (int ks = 0; ks < 2; ++ks) {
      bf16x8 af[4], bfv[4];
#pragma unroll
      for (int i = 0; i < 4; ++i)
        af[i] = *(const bf16x8*)&Als[wm * 64 + i * 16 + (lane & 15)][ks * 32 + (lane >> 4) * 8];
#pragma unroll
      for (int j = 0; j < 4; ++j)
        bfv[j] = *(const bf16x8*)&Bls[wn * 64 + j * 16 + (lane & 15)][ks * 32 + (lane >> 4) * 8];
#pragma unroll
      for (int i = 0; i < 4; ++i)
#pragma unroll
        for (int j = 0; j < 4; ++j)
          acc[i][j] = __builtin_amdgcn_mfma_f32_16x16x32_bf16(af[i], bfv[j], acc[i][j], 0, 0, 0);
    }
    __syncthreads();
  }

  // epilogue: C/D layout col=lane&15, row=(lane>>4)*4+e
#pragma unroll
  for (int i = 0; i < 4; ++i) {
#pragma unroll
    for (int j = 0; j < 4; ++j) {
#pragma unroll
      for (int e = 0; e < 4; ++e) {
        int m = m0 + wm * 64 + i * 16 + (lane >> 4) * 4 + e;
        int n = n0 + wn * 64 + j * 16 + (lane & 15);
        float v = acc[i][j][e] + bias[n];
        if (QKV) {
          int b = m >> 11, t = m & 2047;
          int which = n >> 10, hn = n & 1023;
          int h = hn >> 6, d = hn & 63;
          bf16_t* dst = (which == 0) ? Qb : (which == 1) ? Kb : Vb;
          dst[(((size_t)(b * 16 + h)) * 2048 + t) * 64 + d] = (bf16_t)v;
        } else {
          Out[(size_t)m * 1024 + n] = v;
        }
      }
    }
  }
}

// ---------------- flash attention, causal, hd=64 ---------------------------
// grid (32 qblocks, 32 bh); block 256 = 4 waves; each wave owns 16 q rows.
__global__ __launch_bounds__(256) void attn_fwd(
    const bf16_t* __restrict__ Qb, const bf16_t* __restrict__ Kb,
    const bf16_t* __restrict__ Vb, bf16_t* __restrict__ Ob) {
  const int bh = blockIdx.y;
  const int b = bh >> 4, h = bh & 15;
  const int q0 = blockIdx.x * 64;
  const int tid = threadIdx.x, lane = tid & 63, w = tid >> 6;
  const int g = lane >> 4;       // k-group 0..3
  const int lr = lane & 15;      // 0..15
  const bf16_t* Qp = Qb + (size_t)bh * 2048 * 64;
  const bf16_t* Kp = Kb + (size_t)bh * 2048 * 64;
  const bf16_t* Vp = Vb + (size_t)bh * 2048 * 64;
  __shared__ bf16_t Vt[64][72];      // V^T tile: Vt[d][kj]
  __shared__ bf16_t Pl[4][16][72];   // per-wave P

  bf16x8 qf[2];
  {
    const bf16_t* qsrc = Qp + (size_t)(q0 + w * 16 + lr) * 64 + g * 8;
    qf[0] = *(const bf16x8*)(qsrc);
    qf[1] = *(const bf16x8*)(qsrc + 32);
  }
  float m_run[4] = {-3e38f, -3e38f, -3e38f, -3e38f};
  float l_run[4] = {0.f, 0.f, 0.f, 0.f};
  f32x4 oacc[4] = {};
  const int ktiles = blockIdx.x + 1;
  const float sc = 0.125f * LOG2E;
  const int rbase = q0 + w * 16 + g * 4;

  for (int kt = 0; kt < ktiles; ++kt) {
    const int k0 = kt * 64;
    {  // stage V^T cooperatively
      int kj = tid >> 2, dc = (tid & 3) * 16;
      const bf16_t* vsrc = Vp + (size_t)(k0 + kj) * 64 + dc;
      bf16x8 v0 = *(const bf16x8*)(vsrc);
      bf16x8 v1 = *(const bf16x8*)(vsrc + 8);
#pragma unroll
      for (int e = 0; e < 8; ++e) {
        Vt[dc + e][kj] = v0[e];
        Vt[dc + 8 + e][kj] = v1[e];
      }
    }
    __syncthreads();

    // S = Q K^T  (16 x 64 per wave)
    f32x4 s[4] = {};
#pragma unroll
    for (int ks = 0; ks < 2; ++ks) {
#pragma unroll
      for (int fc = 0; fc < 4; ++fc) {
        bf16x8 kf = *(const bf16x8*)(Kp + (size_t)(k0 + fc * 16 + lr) * 64 + ks * 32 + g * 8);
        s[fc] = __builtin_amdgcn_mfma_f32_16x16x32_bf16(qf[ks], kf, s[fc], 0, 0, 0);
      }
    }

    // scale + causal mask + row max
    float mloc[4] = {-3e38f, -3e38f, -3e38f, -3e38f};
#pragma unroll
    for (int fc = 0; fc < 4; ++fc) {
      int col = k0 + fc * 16 + lr;
#pragma unroll
      for (int e = 0; e < 4; ++e) {
        float v = s[fc][e] * sc;
        v = (col > rbase + e) ? -3e38f : v;
        s[fc][e] = v;
        mloc[e] = fmaxf(mloc[e], v);
      }
    }
#pragma unroll
    for (int off = 1; off < 16; off <<= 1)
#pragma unroll
      for (int e = 0; e < 4; ++e)
        mloc[e] = fmaxf(mloc[e], __shfl_xor(mloc[e], off, 64));

    float rsc[4];
#pragma unroll
    for (int e = 0; e < 4; ++e) {
      float mn = fmaxf(m_run[e], mloc[e]);
      rsc[e] = __builtin_amdgcn_exp2f(m_run[e] - mn);
      m_run[e] = mn;
    }
    float ls[4] = {0.f, 0.f, 0.f, 0.f};
#pragma unroll
    for (int fc = 0; fc < 4; ++fc) {
#pragma unroll
      for (int e = 0; e < 4; ++e) {
        float p = __builtin_amdgcn_exp2f(s[fc][e] - m_run[e]);
        ls[e] += p;
        Pl[w][g * 4 + e][fc * 16 + lr] = (bf16_t)p;
      }
    }
#pragma unroll
    for (int off = 1; off < 16; off <<= 1)
#pragma unroll
      for (int e = 0; e < 4; ++e)
        ls[e] += __shfl_xor(ls[e], off, 64);
#pragma unroll
    for (int e = 0; e < 4; ++e)
      l_run[e] = l_run[e] * rsc[e] + ls[e];
#pragma unroll
    for (int fc2 = 0; fc2 < 4; ++fc2)
#pragma unroll
      for (int e = 0; e < 4; ++e)
        oacc[fc2][e] *= rsc[e];
    __syncthreads();  // make P (cross-lane) + Vt visible

    // O += P @ V
#pragma unroll
    for (int ks = 0; ks < 2; ++ks) {
      bf16x8 pa = *(const bf16x8*)&Pl[w][lr][ks * 32 + g * 8];
#pragma unroll
      for (int fc2 = 0; fc2 < 4; ++fc2) {
        bf16x8 vf = *(const bf16x8*)&Vt[fc2 * 16 + lr][ks * 32 + g * 8];
        oacc[fc2] = __builtin_amdgcn_mfma_f32_16x16x32_bf16(pa, vf, oacc[fc2], 0, 0, 0);
      }
    }
    __syncthreads();  // protect Vt/Pl before next tile's staging
  }

  // write O (bf16) in [B][T][C] layout
#pragma unroll
  for (int fc2 = 0; fc2 < 4; ++fc2) {
#pragma unroll
    for (int e = 0; e < 4; ++e) {
      int t = q0 + w * 16 + g * 4 + e;
      int dcol = h * 64 + fc2 * 16 + lr;
      Ob[((size_t)(b * 2048 + t)) * 1024 + dcol] = (bf16_t)(oacc[fc2][e] / l_run[e]);
    }
  }
}

// ---------------------------------------------------------------------------
extern "C" void kernel_launch(void* const* d_in, const int* in_sizes, int n_in,
                              void* d_out, int out_size, void* d_ws, size_t ws_size,
                              hipStream_t stream) {
  const float* x      = (const float*)d_in[0];
  const float* W_attn = (const float*)d_in[1];
  const float* b_attn = (const float*)d_in[2];
  const float* A_attn = (const float*)d_in[3];
  const float* B_attn = (const float*)d_in[4];
  const float* W_proj = (const float*)d_in[5];
  const float* b_proj = (const float*)d_in[6];
  const float* A_proj = (const float*)d_in[7];
  const float* B_proj = (const float*)d_in[8];
  float* out = (float*)d_out;

  char* ws = (char*)d_ws;
  bf16_t* WaE = (bf16_t*)(ws);               // 3072*1024*2 = 6291456
  bf16_t* WpE = (bf16_t*)(ws + 6291456);     // 1024*1024*2 = 2097152
  bf16_t* Xb  = (bf16_t*)(ws + 8388608);     // 4096*1024*2 = 8388608
  bf16_t* Qb  = (bf16_t*)(ws + 16777216);    // [B*H][T][64]
  bf16_t* Kb  = (bf16_t*)(ws + 25165824);
  bf16_t* Vb  = (bf16_t*)(ws + 33554432);
  bf16_t* Ob  = (bf16_t*)(ws + 41943040);    // [B*T][C] bf16

  prep_weff<<<12288, 256, 0, stream>>>(W_attn, B_attn, A_attn, WaE, 3072 * 1024);
  prep_weff<<<4096, 256, 0, stream>>>(W_proj, B_proj, A_proj, WpE, 1024 * 1024);
  cast_bf<<<16384, 256, 0, stream>>>(x, Xb, 4096 * 1024);

  gemm_bt<true><<<dim3(32, 24), 256, 0, stream>>>(Xb, WaE, b_attn, Qb, Kb, Vb, nullptr);
  attn_fwd<<<dim3(32, 32), 256, 0, stream>>>(Qb, Kb, Vb, Ob);
  gemm_bt<false><<<dim3(32, 8), 256, 0, stream>>>(Ob, WpE, b_proj, nullptr, nullptr, nullptr, out);
}

// Round 2
// 144.574 us; speedup vs baseline: 1.5949x; 1.5949x over previous
//
#include <hip/hip_runtime.h>
#include <hip/hip_bf16.h>
#include <stdint.h>

typedef __bf16 bf16_t;
typedef __bf16 bf16x8 __attribute__((ext_vector_type(8)));
typedef __bf16 bf16x4 __attribute__((ext_vector_type(4)));
typedef float f32x4 __attribute__((ext_vector_type(4)));
typedef uint32_t u32;

#define LOG2E 1.44269504088896340736f

// ---------------- prep: W_eff = W + 2.0 * B @ A  (fold LoRA), cast bf16 ----
__global__ void prep_weff(const float* __restrict__ W,
                          const float* __restrict__ Bm,   // [O][8]
                          const float* __restrict__ Am,   // [8][1024]
                          bf16_t* __restrict__ Weff, int OC) {
  int idx = blockIdx.x * 256 + threadIdx.x;
  if (idx >= OC) return;
  int o = idx >> 10, c = idx & 1023;
  float acc = W[idx];
#pragma unroll
  for (int r = 0; r < 8; ++r)
    acc += 2.0f * Bm[o * 8 + r] * Am[r * 1024 + c];
  Weff[idx] = (bf16_t)acc;
}

__global__ void cast_bf(const float* __restrict__ X, bf16_t* __restrict__ Xb, int n) {
  int i = blockIdx.x * 256 + threadIdx.x;
  if (i < n) Xb[i] = (bf16_t)X[i];
}

// ---------------- GEMM: C[m][n] = sum_k A[m][k] * Bt[n][k] + bias[n] -------
// 128x128 tile, BK=64, 4 waves (2x2). LDS linear stride 64 + XOR swizzle
// (chunk ^= row&7) -> conflict-free ds_read_b128 fragment reads.
template <bool QKV>
__global__ __launch_bounds__(256) void gemm_bt(
    const bf16_t* __restrict__ A, const bf16_t* __restrict__ Bt,
    const float* __restrict__ bias,
    bf16_t* __restrict__ Qb, bf16_t* __restrict__ Kb, bf16_t* __restrict__ Vb,
    float* __restrict__ Out) {
  constexpr int Kdim = 1024;
  __shared__ bf16_t Als[128][64];
  __shared__ bf16_t Bls[128][64];
  const int m0 = blockIdx.x * 128;
  const int n0 = blockIdx.y * 128;
  const int tid = threadIdx.x;
  const int lane = tid & 63;
  const int w = tid >> 6;
  const int wm = w >> 1, wn = w & 1;
  const int lr = lane & 15, g = lane >> 4;
  const int sw = (lane & 7) << 3;

  f32x4 acc[4][4] = {};

  for (int k0 = 0; k0 < Kdim; k0 += 64) {
#pragma unroll
    for (int u = 0; u < 2; ++u) {
      int row = (tid >> 2) + u * 64;
      int c0 = (tid & 3) * 2;
      int r7 = row & 7;
      const bf16_t* pa = A + (size_t)(m0 + row) * Kdim + k0 + c0 * 8;
      const bf16_t* pb = Bt + (size_t)(n0 + row) * Kdim + k0 + c0 * 8;
      int4 va0 = *(const int4*)(pa);
      int4 va1 = *(const int4*)(pa + 8);
      int4 vb0 = *(const int4*)(pb);
      int4 vb1 = *(const int4*)(pb + 8);
      *(int4*)&Als[row][(c0 ^ r7) * 8] = va0;
      *(int4*)&Als[row][((c0 + 1) ^ r7) * 8] = va1;
      *(int4*)&Bls[row][(c0 ^ r7) * 8] = vb0;
      *(int4*)&Bls[row][((c0 + 1) ^ r7) * 8] = vb1;
    }
    __syncthreads();
#pragma unroll
    for (int ks = 0; ks < 2; ++ks) {
      bf16x8 af[4], bfv[4];
#pragma unroll
      for (int i = 0; i < 4; ++i)
        af[i] = *(const bf16x8*)&Als[wm * 64 + i * 16 + lr][(ks * 32 + g * 8) ^ sw];
#pragma unroll
      for (int j = 0; j < 4; ++j)
        bfv[j] = *(const bf16x8*)&Bls[wn * 64 + j * 16 + lr][(ks * 32 + g * 8) ^ sw];
#pragma unroll
      for (int i = 0; i < 4; ++i)
#pragma unroll
        for (int j = 0; j < 4; ++j)
          acc[i][j] = __builtin_amdgcn_mfma_f32_16x16x32_bf16(af[i], bfv[j], acc[i][j], 0, 0, 0);
    }
    __syncthreads();
  }

  // epilogue: C/D layout col=lane&15, row=(lane>>4)*4+e
#pragma unroll
  for (int i = 0; i < 4; ++i) {
#pragma unroll
    for (int j = 0; j < 4; ++j) {
#pragma unroll
      for (int e = 0; e < 4; ++e) {
        int m = m0 + wm * 64 + i * 16 + g * 4 + e;
        int n = n0 + wn * 64 + j * 16 + lr;
        float v = acc[i][j][e] + bias[n];
        if (QKV) {
          int b = m >> 11, t = m & 2047;
          int which = n >> 10, hn = n & 1023;
          int h = hn >> 6, d = hn & 63;
          bf16_t* dst = (which == 0) ? Qb : (which == 1) ? Kb : Vb;
          dst[(((size_t)(b * 16 + h)) * 2048 + t) * 64 + d] = (bf16_t)v;
        } else {
          Out[(size_t)m * 1024 + n] = v;
        }
      }
    }
  }
}

// ---------------- flash attention, causal, hd=64, KVBLK=128 ----------------
// grid (16, 32): pair index x (q-blocks pr and 31-pr), bh y, XCD-chunked.
// 4 waves x 16 q-rows. Swapped QK^T (S^T = K*Q^T) -> lane-local softmax.
__global__ __launch_bounds__(256) void attn_fwd(
    const bf16_t* __restrict__ Qb, const bf16_t* __restrict__ Kb,
    const bf16_t* __restrict__ Vb, bf16_t* __restrict__ Ob) {
  __shared__ bf16_t Kls[128][64];   // K rows, swizzled chunks
  __shared__ bf16_t Vt[64][128];    // V^T [d][k], swizzled chunks
  __shared__ bf16_t Pl[4][16][128]; // per-wave P [q][k], swizzled chunks

  int id = blockIdx.y * 16 + blockIdx.x;          // 0..511
  int nid = (id & 7) * 64 + (id >> 3);            // XCD-chunked (bijective)
  int bh = nid >> 4, pr = nid & 15;
  int b = bh >> 4, h = bh & 15;

  const int tid = threadIdx.x, lane = tid & 63, w = tid >> 6;
  const int g = lane >> 4, lr = lane & 15;
  const int sw = (lane & 7) << 3;
  const bf16_t* Qp = Qb + (size_t)bh * 2048 * 64;
  const bf16_t* Kp = Kb + (size_t)bh * 2048 * 64;
  const bf16_t* Vp = Vb + (size_t)bh * 2048 * 64;
  const float sc = 0.125f * LOG2E;

  for (int pass = 0; pass < 2; ++pass) {
    const int qb = pass ? (31 - pr) : pr;
    const int q0 = qb * 64;
    const int qrow = q0 + w * 16 + lr;
    bf16x8 qf0, qf1;
    {
      const bf16_t* qsrc = Qp + (size_t)qrow * 64 + g * 8;
      qf0 = *(const bf16x8*)(qsrc);
      qf1 = *(const bf16x8*)(qsrc + 32);
    }
    float m_run = -3e38f, l_run = 0.f;
    f32x4 oacc[4] = {};
    const int ktiles = (qb >> 1) + 1;

    for (int kt = 0; kt < ktiles; ++kt) {
      const int k0 = kt * 128;
      __syncthreads();  // previous tile/pass readers done before restage

      // ---- stage K: [128][64], swizzled, b128 writes ----
#pragma unroll
      for (int u = 0; u < 2; ++u) {
        int row = (tid >> 2) + u * 64;
        int r7 = row & 7;
        const bf16_t* src = Kp + (size_t)(k0 + row) * 64 + (tid & 3) * 16;
        int4 v0 = *(const int4*)(src);
        int4 v1 = *(const int4*)(src + 8);
        int c0 = (tid & 3) * 2;
        *(int4*)&Kls[row][(c0 ^ r7) * 8] = v0;
        *(int4*)&Kls[row][((c0 + 1) ^ r7) * 8] = v1;
      }

      // ---- stage V^T: in-register 8x4 transpose via v_perm ----
      {
        int kbase = (tid >> 4) * 8;   // 0..120
        int dbase = (tid & 15) * 4;   // 0..60
        uint2 rowv[8];
#pragma unroll
        for (int r = 0; r < 8; ++r)
          rowv[r] = *(const uint2*)(Vp + (size_t)(k0 + kbase + r) * 64 + dbase);
#pragma unroll
        for (int dd = 0; dd < 4; ++dd) {
          u32 sel = (dd & 1) ? 0x07060302u : 0x05040100u;
          u32 a0 = (dd >> 1) ? rowv[0].y : rowv[0].x;
          u32 a1 = (dd >> 1) ? rowv[1].y : rowv[1].x;
          u32 a2 = (dd >> 1) ? rowv[2].y : rowv[2].x;
          u32 a3 = (dd >> 1) ? rowv[3].y : rowv[3].x;
          u32 a4 = (dd >> 1) ? rowv[4].y : rowv[4].x;
          u32 a5 = (dd >> 1) ? rowv[5].y : rowv[5].x;
          u32 a6 = (dd >> 1) ? rowv[6].y : rowv[6].x;
          u32 a7 = (dd >> 1) ? rowv[7].y : rowv[7].x;
          int4 val;
          val.x = __builtin_amdgcn_perm(a1, a0, sel);
          val.y = __builtin_amdgcn_perm(a3, a2, sel);
          val.z = __builtin_amdgcn_perm(a5, a4, sel);
          val.w = __builtin_amdgcn_perm(a7, a6, sel);
          int d = dbase + dd;
          *(int4*)&Vt[d][kbase ^ ((d & 7) << 3)] = val;
        }
      }
      __syncthreads();

      // ---- QK^T (swapped): S^T[kk][q] fragments ----
      f32x4 sacc[8];
#pragma unroll
      for (int fa = 0; fa < 8; ++fa) {
        sacc[fa] = (f32x4){0.f, 0.f, 0.f, 0.f};
        int row = fa * 16 + lr;
        bf16x8 kf0 = *(const bf16x8*)&Kls[row][(g * 8) ^ sw];
        bf16x8 kf1 = *(const bf16x8*)&Kls[row][(32 + g * 8) ^ sw];
        sacc[fa] = __builtin_amdgcn_mfma_f32_16x16x32_bf16(kf0, qf0, sacc[fa], 0, 0, 0);
        sacc[fa] = __builtin_amdgcn_mfma_f32_16x16x32_bf16(kf1, qf1, sacc[fa], 0, 0, 0);
      }

      // ---- softmax: lane owns q=qrow, 32 kk values ----
      const bool lastt = (kt == ktiles - 1);
      float mloc = -3e38f;
#pragma unroll
      for (int fa = 0; fa < 8; ++fa) {
#pragma unroll
        for (int e = 0; e < 4; ++e) {
          float v = sacc[fa][e] * sc;
          if (lastt) {
            int kkg = k0 + fa * 16 + g * 4 + e;
            v = (kkg > qrow) ? -3e38f : v;
          }
          sacc[fa][e] = v;
          mloc = fmaxf(mloc, v);
        }
      }
      mloc = fmaxf(mloc, __shfl_xor(mloc, 16, 64));
      mloc = fmaxf(mloc, __shfl_xor(mloc, 32, 64));
      float mnew = fmaxf(m_run, mloc);
      float rsc = __builtin_amdgcn_exp2f(m_run - mnew);
      m_run = mnew;

      float lsum = 0.f;
#pragma unroll
      for (int fa = 0; fa < 8; ++fa) {
        float p0 = __builtin_amdgcn_exp2f(sacc[fa][0] - mnew);
        float p1 = __builtin_amdgcn_exp2f(sacc[fa][1] - mnew);
        float p2 = __builtin_amdgcn_exp2f(sacc[fa][2] - mnew);
        float p3 = __builtin_amdgcn_exp2f(sacc[fa][3] - mnew);
        lsum += (p0 + p1) + (p2 + p3);
        bf16x4 pv = {(bf16_t)p0, (bf16_t)p1, (bf16_t)p2, (bf16_t)p3};
        *(bf16x4*)&Pl[w][lr][(fa * 16 + g * 4) ^ ((lr & 7) << 3)] = pv;
      }
      lsum += __shfl_xor(lsum, 16, 64);
      lsum += __shfl_xor(lsum, 32, 64);
      l_run = l_run * rsc + lsum;

      // rescale O (factor for this fragment row q = g*4+e)
      float rsc_e[4];
#pragma unroll
      for (int e = 0; e < 4; ++e) rsc_e[e] = __shfl(rsc, g * 4 + e, 64);
#pragma unroll
      for (int fc2 = 0; fc2 < 4; ++fc2)
#pragma unroll
        for (int e = 0; e < 4; ++e) oacc[fc2][e] *= rsc_e[e];

      // wave-local P visibility (no block barrier needed: Pl[w] is per-wave)
      asm volatile("s_waitcnt lgkmcnt(0)" ::: "memory");
      __builtin_amdgcn_sched_barrier(0);

      // ---- O += P @ V ----
#pragma unroll
      for (int ks = 0; ks < 4; ++ks) {
        bf16x8 pa = *(const bf16x8*)&Pl[w][lr][(ks * 32 + g * 8) ^ sw];
#pragma unroll
        for (int fc2 = 0; fc2 < 4; ++fc2) {
          bf16x8 vf = *(const bf16x8*)&Vt[fc2 * 16 + lr][(ks * 32 + g * 8) ^ sw];
          oacc[fc2] = __builtin_amdgcn_mfma_f32_16x16x32_bf16(pa, vf, oacc[fc2], 0, 0, 0);
        }
      }
    }  // kt

    // epilogue: O[q][d], q = g*4+e, d = fc2*16+lr
    float l_e[4];
#pragma unroll
    for (int e = 0; e < 4; ++e) l_e[e] = __shfl(l_run, g * 4 + e, 64);
#pragma unroll
    for (int fc2 = 0; fc2 < 4; ++fc2) {
#pragma unroll
      for (int e = 0; e < 4; ++e) {
        int t = q0 + w * 16 + g * 4 + e;
        int dcol = h * 64 + fc2 * 16 + lr;
        Ob[((size_t)(b * 2048 + t)) * 1024 + dcol] = (bf16_t)(oacc[fc2][e] / l_e[e]);
      }
    }
  }  // pass
}

// ---------------------------------------------------------------------------
extern "C" void kernel_launch(void* const* d_in, const int* in_sizes, int n_in,
                              void* d_out, int out_size, void* d_ws, size_t ws_size,
                              hipStream_t stream) {
  const float* x      = (const float*)d_in[0];
  const float* W_attn = (const float*)d_in[1];
  const float* b_attn = (const float*)d_in[2];
  const float* A_attn = (const float*)d_in[3];
  const float* B_attn = (const float*)d_in[4];
  const float* W_proj = (const float*)d_in[5];
  const float* b_proj = (const float*)d_in[6];
  const float* A_proj = (const float*)d_in[7];
  const float* B_proj = (const float*)d_in[8];
  float* out = (float*)d_out;

  char* ws = (char*)d_ws;
  bf16_t* WaE = (bf16_t*)(ws);               // 3072*1024*2 = 6291456
  bf16_t* WpE = (bf16_t*)(ws + 6291456);     // 1024*1024*2 = 2097152
  bf16_t* Xb  = (bf16_t*)(ws + 8388608);     // 4096*1024*2 = 8388608
  bf16_t* Qb  = (bf16_t*)(ws + 16777216);    // [B*H][T][64]
  bf16_t* Kb  = (bf16_t*)(ws + 25165824);
  bf16_t* Vb  = (bf16_t*)(ws + 33554432);
  bf16_t* Ob  = (bf16_t*)(ws + 41943040);    // [B*T][C] bf16

  prep_weff<<<12288, 256, 0, stream>>>(W_attn, B_attn, A_attn, WaE, 3072 * 1024);
  prep_weff<<<4096, 256, 0, stream>>>(W_proj, B_proj, A_proj, WpE, 1024 * 1024);
  cast_bf<<<16384, 256, 0, stream>>>(x, Xb, 4096 * 1024);

  gemm_bt<true><<<dim3(32, 24), 256, 0, stream>>>(Xb, WaE, b_attn, Qb, Kb, Vb, nullptr);
  attn_fwd<<<dim3(16, 32), 256, 0, stream>>>(Qb, Kb, Vb, Ob);
  gemm_bt<false><<<dim3(32, 8), 256, 0, stream>>>(Ob, WpE, b_proj, nullptr, nullptr, nullptr, out);
}

// Round 3
// 136.663 us; speedup vs baseline: 1.6872x; 1.0579x over previous
//
#include <hip/hip_runtime.h>
#include <hip/hip_bf16.h>
#include <stdint.h>

typedef __bf16 bf16_t;
typedef __bf16 bf16x8 __attribute__((ext_vector_type(8)));
typedef __bf16 bf16x4 __attribute__((ext_vector_type(4)));
typedef float f32x4 __attribute__((ext_vector_type(4)));
typedef uint32_t u32;

#define LOG2E 1.44269504088896340736f

// ---------------- prep: W_eff = W + 2.0 * B @ A  (fold LoRA), cast bf16 ----
__global__ void prep_weff(const float* __restrict__ W,
                          const float* __restrict__ Bm,   // [O][8]
                          const float* __restrict__ Am,   // [8][1024]
                          bf16_t* __restrict__ Weff, int OC) {
  int idx = blockIdx.x * 256 + threadIdx.x;
  if (idx >= OC) return;
  int o = idx >> 10, c = idx & 1023;
  float acc = W[idx];
#pragma unroll
  for (int r = 0; r < 8; ++r)
    acc += 2.0f * Bm[o * 8 + r] * Am[r * 1024 + c];
  Weff[idx] = (bf16_t)acc;
}

__global__ void cast_bf(const float* __restrict__ X, bf16_t* __restrict__ Xb, int n) {
  int i = blockIdx.x * 256 + threadIdx.x;
  if (i < n) Xb[i] = (bf16_t)X[i];
}

// ---------------- GEMM: C[m][n] = sum_k A[m][k] * Bt[n][k] + bias[n] -------
template <bool QKV>
__global__ __launch_bounds__(256) void gemm_bt(
    const bf16_t* __restrict__ A, const bf16_t* __restrict__ Bt,
    const float* __restrict__ bias,
    bf16_t* __restrict__ Qb, bf16_t* __restrict__ Kb, bf16_t* __restrict__ Vb,
    float* __restrict__ Out) {
  constexpr int Kdim = 1024;
  __shared__ bf16_t Als[128][64];
  __shared__ bf16_t Bls[128][64];
  const int m0 = blockIdx.x * 128;
  const int n0 = blockIdx.y * 128;
  const int tid = threadIdx.x;
  const int lane = tid & 63;
  const int w = tid >> 6;
  const int wm = w >> 1, wn = w & 1;
  const int lr = lane & 15, g = lane >> 4;
  const int sw = (lane & 7) << 3;

  f32x4 acc[4][4] = {};

  for (int k0 = 0; k0 < Kdim; k0 += 64) {
#pragma unroll
    for (int u = 0; u < 2; ++u) {
      int row = (tid >> 2) + u * 64;
      int c0 = (tid & 3) * 2;
      int r7 = row & 7;
      const bf16_t* pa = A + (size_t)(m0 + row) * Kdim + k0 + c0 * 8;
      const bf16_t* pb = Bt + (size_t)(n0 + row) * Kdim + k0 + c0 * 8;
      int4 va0 = *(const int4*)(pa);
      int4 va1 = *(const int4*)(pa + 8);
      int4 vb0 = *(const int4*)(pb);
      int4 vb1 = *(const int4*)(pb + 8);
      *(int4*)&Als[row][(c0 ^ r7) * 8] = va0;
      *(int4*)&Als[row][((c0 + 1) ^ r7) * 8] = va1;
      *(int4*)&Bls[row][(c0 ^ r7) * 8] = vb0;
      *(int4*)&Bls[row][((c0 + 1) ^ r7) * 8] = vb1;
    }
    __syncthreads();
#pragma unroll
    for (int ks = 0; ks < 2; ++ks) {
      bf16x8 af[4], bfv[4];
#pragma unroll
      for (int i = 0; i < 4; ++i)
        af[i] = *(const bf16x8*)&Als[wm * 64 + i * 16 + lr][(ks * 32 + g * 8) ^ sw];
#pragma unroll
      for (int j = 0; j < 4; ++j)
        bfv[j] = *(const bf16x8*)&Bls[wn * 64 + j * 16 + lr][(ks * 32 + g * 8) ^ sw];
#pragma unroll
      for (int i = 0; i < 4; ++i)
#pragma unroll
        for (int j = 0; j < 4; ++j)
          acc[i][j] = __builtin_amdgcn_mfma_f32_16x16x32_bf16(af[i], bfv[j], acc[i][j], 0, 0, 0);
    }
    __syncthreads();
  }

#pragma unroll
  for (int i = 0; i < 4; ++i) {
#pragma unroll
    for (int j = 0; j < 4; ++j) {
#pragma unroll
      for (int e = 0; e < 4; ++e) {
        int m = m0 + wm * 64 + i * 16 + g * 4 + e;
        int n = n0 + wn * 64 + j * 16 + lr;
        float v = acc[i][j][e] + bias[n];
        if (QKV) {
          int b = m >> 11, t = m & 2047;
          int which = n >> 10, hn = n & 1023;
          int h = hn >> 6, d = hn & 63;
          bf16_t* dst = (which == 0) ? Qb : (which == 1) ? Kb : Vb;
          dst[(((size_t)(b * 16 + h)) * 2048 + t) * 64 + d] = (bf16_t)v;
        } else {
          Out[(size_t)m * 1024 + n] = v;
        }
      }
    }
  }
}

// ---------------- flash attention, causal, hd=64 ---------------------------
// QBLK=128 (2 q-groups/wave), KVBLK=128, 4 waves, 512 blocks.
__global__ __launch_bounds__(256, 2) void attn_fwd(
    const bf16_t* __restrict__ Qb, const bf16_t* __restrict__ Kb,
    const bf16_t* __restrict__ Vb, bf16_t* __restrict__ Ob) {
  __shared__ bf16_t Kls[128][64];      // K tile, row-key swizzle
  __shared__ bf16_t Vt[64][128];       // V^T [d][k], d-key swizzle
  __shared__ bf16_t Pl[4][2][16][128]; // per-wave, per-group P

  // XCD-aware, load-balanced mapping: 64 blocks/XCD = 4 bh x 16 qb;
  // slots j and j+32 (likely same CU) get qb and 15-qb.
  int id = blockIdx.x;
  int xcd = id & 7, j = id >> 3;
  int lo = j & 31, hi = j >> 5;
  int bh = xcd * 4 + (lo & 3);
  int qb = hi ? 15 - (lo >> 2) : (lo >> 2);
  int b = bh >> 4, h = bh & 15;

  const int tid = threadIdx.x, lane = tid & 63, w = tid >> 6;
  const int g = lane >> 4, lr = lane & 15;
  const int sw = (lane & 7) << 3;
  const bf16_t* Qp = Qb + (size_t)bh * 2048 * 64;
  const bf16_t* Kp = Kb + (size_t)bh * 2048 * 64;
  const bf16_t* Vp = Vb + (size_t)bh * 2048 * 64;
  const float sc = 0.125f * LOG2E;

  const int q0 = qb * 128;
  const int qrow0 = q0 + w * 16 + lr;
  const int qrow1 = qrow0 + 64;

  bf16x8 qf[2][2];
#pragma unroll
  for (int grp = 0; grp < 2; ++grp) {
    const bf16_t* qsrc = Qp + (size_t)(qrow0 + grp * 64) * 64 + g * 8;
    qf[grp][0] = *(const bf16x8*)(qsrc);
    qf[grp][1] = *(const bf16x8*)(qsrc + 32);
  }

  // per-fc2 V^T read keys: key(d) = ((d&7) ^ ((d>>2)&7)) << 3, d = fc2*16+lr
  int vkey[4];
#pragma unroll
  for (int fc2 = 0; fc2 < 4; ++fc2)
    vkey[fc2] = (((lr & 7) ^ ((fc2 * 4 + (lr >> 2)) & 7)) << 3);

  float m_run[2] = {-3e38f, -3e38f};
  float l_run[2] = {0.f, 0.f};
  f32x4 o0[4] = {}, o1[4] = {};
  const int ktiles = qb + 1;

  for (int kt = 0; kt < ktiles; ++kt) {
    const int k0 = kt * 128;
    const bool lastt = (kt == ktiles - 1);
    __syncthreads();  // prior tile's readers done

    // ---- stage K [128][64], row-key swizzle ----
#pragma unroll
    for (int u = 0; u < 2; ++u) {
      int row = (tid >> 2) + u * 64;
      int r7 = row & 7;
      const bf16_t* src = Kp + (size_t)(k0 + row) * 64 + (tid & 3) * 16;
      int4 v0 = *(const int4*)(src);
      int4 v1 = *(const int4*)(src + 8);
      int c0 = (tid & 3) * 2;
      *(int4*)&Kls[row][(c0 ^ r7) * 8] = v0;
      *(int4*)&Kls[row][((c0 + 1) ^ r7) * 8] = v1;
    }

    // ---- stage V^T with d-key swizzle (conflict-free write AND read) ----
    {
      int kbase = (tid >> 4) * 8;   // 0..120
      int dbase = (tid & 15) * 4;   // 0..60
      uint2 rowv[8];
#pragma unroll
      for (int r = 0; r < 8; ++r)
        rowv[r] = *(const uint2*)(Vp + (size_t)(k0 + kbase + r) * 64 + dbase);
#pragma unroll
      for (int dd = 0; dd < 4; ++dd) {
        u32 sel = (dd & 1) ? 0x07060302u : 0x05040100u;
        u32 a0 = (dd >> 1) ? rowv[0].y : rowv[0].x;
        u32 a1 = (dd >> 1) ? rowv[1].y : rowv[1].x;
        u32 a2 = (dd >> 1) ? rowv[2].y : rowv[2].x;
        u32 a3 = (dd >> 1) ? rowv[3].y : rowv[3].x;
        u32 a4 = (dd >> 1) ? rowv[4].y : rowv[4].x;
        u32 a5 = (dd >> 1) ? rowv[5].y : rowv[5].x;
        u32 a6 = (dd >> 1) ? rowv[6].y : rowv[6].x;
        u32 a7 = (dd >> 1) ? rowv[7].y : rowv[7].x;
        int4 val;
        val.x = __builtin_amdgcn_perm(a1, a0, sel);
        val.y = __builtin_amdgcn_perm(a3, a2, sel);
        val.z = __builtin_amdgcn_perm(a5, a4, sel);
        val.w = __builtin_amdgcn_perm(a7, a6, sel);
        int d = dbase + dd;
        int key = ((d & 7) ^ ((d >> 2) & 7)) << 3;
        *(int4*)&Vt[d][kbase ^ key] = val;
      }
    }
    __syncthreads();

    // ---- QK^T (swapped): both q-groups share K fragments ----
    f32x4 s0[8] = {}, s1[8] = {};
#pragma unroll
    for (int ks = 0; ks < 2; ++ks) {
      bf16x8 kf[8];
#pragma unroll
      for (int fa = 0; fa < 8; ++fa)
        kf[fa] = *(const bf16x8*)&Kls[fa * 16 + lr][(ks * 32 + g * 8) ^ sw];
#pragma unroll
      for (int fa = 0; fa < 8; ++fa) {
        if (fa < 4 || !lastt)  // grp0 upper half fully masked on last tile
          s0[fa] = __builtin_amdgcn_mfma_f32_16x16x32_bf16(kf[fa], qf[0][ks], s0[fa], 0, 0, 0);
        s1[fa] = __builtin_amdgcn_mfma_f32_16x16x32_bf16(kf[fa], qf[1][ks], s1[fa], 0, 0, 0);
      }
    }

    // ---- softmax group 0 ----
    {
      const int famax = lastt ? 4 : 8;
      float mloc = -3e38f;
#pragma unroll
      for (int fa = 0; fa < 8; ++fa) {
        if (fa < famax) {
#pragma unroll
          for (int e = 0; e < 4; ++e) {
            float v = s0[fa][e] * sc;
            if (lastt) {
              int kk = k0 + fa * 16 + g * 4 + e;
              v = (kk > qrow0) ? -3e38f : v;
            }
            s0[fa][e] = v;
            mloc = fmaxf(mloc, v);
          }
        }
      }
      mloc = fmaxf(mloc, __shfl_xor(mloc, 16, 64));
      mloc = fmaxf(mloc, __shfl_xor(mloc, 32, 64));
      if (!__all(mloc <= m_run[0] + 8.0f)) {
        float mnew = fmaxf(m_run[0], mloc);
        float rs = __builtin_amdgcn_exp2f(m_run[0] - mnew);
        m_run[0] = mnew;
        l_run[0] *= rs;
        float rs_e[4];
#pragma unroll
        for (int e = 0; e < 4; ++e) rs_e[e] = __shfl(rs, g * 4 + e, 64);
#pragma unroll
        for (int fc2 = 0; fc2 < 4; ++fc2)
#pragma unroll
          for (int e = 0; e < 4; ++e) o0[fc2][e] *= rs_e[e];
      }
      float lsum = 0.f;
#pragma unroll
      for (int fa = 0; fa < 8; ++fa) {
        if (fa < famax) {
          float p0 = __builtin_amdgcn_exp2f(s0[fa][0] - m_run[0]);
          float p1 = __builtin_amdgcn_exp2f(s0[fa][1] - m_run[0]);
          float p2 = __builtin_amdgcn_exp2f(s0[fa][2] - m_run[0]);
          float p3 = __builtin_amdgcn_exp2f(s0[fa][3] - m_run[0]);
          lsum += (p0 + p1) + (p2 + p3);
          bf16x4 pv = {(bf16_t)p0, (bf16_t)p1, (bf16_t)p2, (bf16_t)p3};
          *(bf16x4*)&Pl[w][0][lr][(fa * 16 + g * 4) ^ sw] = pv;
        }
      }
      lsum += __shfl_xor(lsum, 16, 64);
      lsum += __shfl_xor(lsum, 32, 64);
      l_run[0] += lsum;
    }

    // ---- softmax group 1 ----
    {
      float mloc = -3e38f;
#pragma unroll
      for (int fa = 0; fa < 8; ++fa) {
#pragma unroll
        for (int e = 0; e < 4; ++e) {
          float v = s1[fa][e] * sc;
          if (lastt) {
            int kk = k0 + fa * 16 + g * 4 + e;
            v = (kk > qrow1) ? -3e38f : v;
          }
          s1[fa][e] = v;
          mloc = fmaxf(mloc, v);
        }
      }
      mloc = fmaxf(mloc, __shfl_xor(mloc, 16, 64));
      mloc = fmaxf(mloc, __shfl_xor(mloc, 32, 64));
      if (!__all(mloc <= m_run[1] + 8.0f)) {
        float mnew = fmaxf(m_run[1], mloc);
        float rs = __builtin_amdgcn_exp2f(m_run[1] - mnew);
        m_run[1] = mnew;
        l_run[1] *= rs;
        float rs_e[4];
#pragma unroll
        for (int e = 0; e < 4; ++e) rs_e[e] = __shfl(rs, g * 4 + e, 64);
#pragma unroll
        for (int fc2 = 0; fc2 < 4; ++fc2)
#pragma unroll
          for (int e = 0; e < 4; ++e) o1[fc2][e] *= rs_e[e];
      }
      float lsum = 0.f;
#pragma unroll
      for (int fa = 0; fa < 8; ++fa) {
        float p0 = __builtin_amdgcn_exp2f(s1[fa][0] - m_run[1]);
        float p1 = __builtin_amdgcn_exp2f(s1[fa][1] - m_run[1]);
        float p2 = __builtin_amdgcn_exp2f(s1[fa][2] - m_run[1]);
        float p3 = __builtin_amdgcn_exp2f(s1[fa][3] - m_run[1]);
        lsum += (p0 + p1) + (p2 + p3);
        bf16x4 pv = {(bf16_t)p0, (bf16_t)p1, (bf16_t)p2, (bf16_t)p3};
        *(bf16x4*)&Pl[w][1][lr][(fa * 16 + g * 4) ^ sw] = pv;
      }
      lsum += __shfl_xor(lsum, 16, 64);
      lsum += __shfl_xor(lsum, 32, 64);
      l_run[1] += lsum;
    }

    // wave-local P visibility
    asm volatile("s_waitcnt lgkmcnt(0)" ::: "memory");
    __builtin_amdgcn_sched_barrier(0);

    // ---- O += P @ V, V-frags shared across groups ----
#pragma unroll
    for (int ks2 = 0; ks2 < 4; ++ks2) {
      bf16x8 vf[4];
#pragma unroll
      for (int fc2 = 0; fc2 < 4; ++fc2)
        vf[fc2] = *(const bf16x8*)&Vt[fc2 * 16 + lr][(ks2 * 32 + g * 8) ^ vkey[fc2]];
      bf16x8 pa1 = *(const bf16x8*)&Pl[w][1][lr][(ks2 * 32 + g * 8) ^ sw];
#pragma unroll
      for (int fc2 = 0; fc2 < 4; ++fc2)
        o1[fc2] = __builtin_amdgcn_mfma_f32_16x16x32_bf16(pa1, vf[fc2], o1[fc2], 0, 0, 0);
      if (ks2 < 2 || !lastt) {
        bf16x8 pa0 = *(const bf16x8*)&Pl[w][0][lr][(ks2 * 32 + g * 8) ^ sw];
#pragma unroll
        for (int fc2 = 0; fc2 < 4; ++fc2)
          o0[fc2] = __builtin_amdgcn_mfma_f32_16x16x32_bf16(pa0, vf[fc2], o0[fc2], 0, 0, 0);
      }
    }
  }  // kt

  // ---- epilogue ----
#pragma unroll
  for (int grp = 0; grp < 2; ++grp) {
    f32x4* oa = grp ? o1 : o0;
    float le[4];
#pragma unroll
    for (int e = 0; e < 4; ++e) le[e] = __shfl(l_run[grp], g * 4 + e, 64);
#pragma unroll
    for (int e = 0; e < 4; ++e) {
      float inv = 1.0f / le[e];
      int t = q0 + grp * 64 + w * 16 + g * 4 + e;
#pragma unroll
      for (int fc2 = 0; fc2 < 4; ++fc2) {
        int dcol = h * 64 + fc2 * 16 + lr;
        Ob[((size_t)(b * 2048 + t)) * 1024 + dcol] = (bf16_t)(oa[fc2][e] * inv);
      }
    }
  }
}

// ---------------------------------------------------------------------------
extern "C" void kernel_launch(void* const* d_in, const int* in_sizes, int n_in,
                              void* d_out, int out_size, void* d_ws, size_t ws_size,
                              hipStream_t stream) {
  const float* x      = (const float*)d_in[0];
  const float* W_attn = (const float*)d_in[1];
  const float* b_attn = (const float*)d_in[2];
  const float* A_attn = (const float*)d_in[3];
  const float* B_attn = (const float*)d_in[4];
  const float* W_proj = (const float*)d_in[5];
  const float* b_proj = (const float*)d_in[6];
  const float* A_proj = (const float*)d_in[7];
  const float* B_proj = (const float*)d_in[8];
  float* out = (float*)d_out;

  char* ws = (char*)d_ws;
  bf16_t* WaE = (bf16_t*)(ws);               // 3072*1024*2
  bf16_t* WpE = (bf16_t*)(ws + 6291456);     // 1024*1024*2
  bf16_t* Xb  = (bf16_t*)(ws + 8388608);     // 4096*1024*2
  bf16_t* Qb  = (bf16_t*)(ws + 16777216);    // [B*H][T][64]
  bf16_t* Kb  = (bf16_t*)(ws + 25165824);
  bf16_t* Vb  = (bf16_t*)(ws + 33554432);
  bf16_t* Ob  = (bf16_t*)(ws + 41943040);    // [B*T][C] bf16

  prep_weff<<<12288, 256, 0, stream>>>(W_attn, B_attn, A_attn, WaE, 3072 * 1024);
  prep_weff<<<4096, 256, 0, stream>>>(W_proj, B_proj, A_proj, WpE, 1024 * 1024);
  cast_bf<<<16384, 256, 0, stream>>>(x, Xb, 4096 * 1024);

  gemm_bt<true><<<dim3(32, 24), 256, 0, stream>>>(Xb, WaE, b_attn, Qb, Kb, Vb, nullptr);
  attn_fwd<<<512, 256, 0, stream>>>(Qb, Kb, Vb, Ob);
  gemm_bt<false><<<dim3(32, 8), 256, 0, stream>>>(Ob, WpE, b_proj, nullptr, nullptr, nullptr, out);
}

// Round 4
// 114.192 us; speedup vs baseline: 2.0192x; 1.1968x over previous
//
#include <hip/hip_runtime.h>
#include <hip/hip_bf16.h>
#include <stdint.h>

typedef __bf16 bf16_t;
typedef __bf16 bf16x8 __attribute__((ext_vector_type(8)));
typedef __bf16 bf16x4 __attribute__((ext_vector_type(4)));
typedef float f32x4 __attribute__((ext_vector_type(4)));
typedef uint32_t u32;

typedef __attribute__((address_space(1))) void as1void;
typedef __attribute__((address_space(3))) void as3void;

#define LOG2E 1.44269504088896340736f

// async 16B/lane global->LDS DMA; LDS dest = wave-uniform base + lane*16
__device__ __forceinline__ void gll16(const void* g, void* l) {
  __builtin_amdgcn_global_load_lds((as1void*)g, (as3void*)l, 16, 0, 0);
}

// ---------------- prep: W_eff = W + 2.0 * B @ A  (fold LoRA), cast bf16 ----
__global__ void prep_weff(const float* __restrict__ W,
                          const float* __restrict__ Bm,   // [O][8]
                          const float* __restrict__ Am,   // [8][1024]
                          bf16_t* __restrict__ Weff, int OC) {
  int idx = blockIdx.x * 256 + threadIdx.x;
  if (idx >= OC) return;
  int o = idx >> 10, c = idx & 1023;
  float acc = W[idx];
#pragma unroll
  for (int r = 0; r < 8; ++r)
    acc += 2.0f * Bm[o * 8 + r] * Am[r * 1024 + c];
  Weff[idx] = (bf16_t)acc;
}

__global__ void cast_bf4(const float4* __restrict__ X, bf16x4* __restrict__ Xb, int n4) {
  int i = blockIdx.x * 256 + threadIdx.x;
  if (i < n4) {
    float4 v = X[i];
    bf16x4 o = {(bf16_t)v.x, (bf16_t)v.y, (bf16_t)v.z, (bf16_t)v.w};
    Xb[i] = o;
  }
}

// ---------------- GEMM: C[m][n] = sum_k A[m][k] * Bt[n][k] + bias[n] -------
// 128x128 tile, BK=64, 4 waves (2x2). global_load_lds staging with
// pre-swizzled source (linear LDS dest); read key = row&7 on 16B chunks.
template <bool QKV>
__global__ __launch_bounds__(256, 3) void gemm_bt(
    const bf16_t* __restrict__ A, const bf16_t* __restrict__ Bt,
    const float* __restrict__ bias,
    bf16_t* __restrict__ Qb, bf16_t* __restrict__ Kb, bf16_t* __restrict__ Vb,
    float* __restrict__ Out) {
  __shared__ bf16_t Als[128][64];
  __shared__ bf16_t Bls[128][64];
  const int m0 = blockIdx.x * 128;
  const int n0 = blockIdx.y * 128;
  const int tid = threadIdx.x;
  const int lane = tid & 63;
  const int w = tid >> 6;
  const int wm = w >> 1, wn = w & 1;
  const int lr = lane & 15, g = lane >> 4;
  const int sw = (lane & 7) << 3;
  const int srow = lane >> 3;                 // 0..7
  const int soff = ((lane & 7) ^ srow) * 8;   // pre-swizzled source chunk

  f32x4 acc[4][4] = {};

  for (int k0 = 0; k0 < 1024; k0 += 64) {
#pragma unroll
    for (int c = 0; c < 4; ++c) {
      int r = w * 32 + c * 8 + srow;
      gll16(A + (size_t)(m0 + r) * 1024 + k0 + soff, &Als[w * 32 + c * 8][0]);
      gll16(Bt + (size_t)(n0 + r) * 1024 + k0 + soff, &Bls[w * 32 + c * 8][0]);
    }
    __syncthreads();
#pragma unroll
    for (int ks = 0; ks < 2; ++ks) {
      bf16x8 af[4], bfv[4];
#pragma unroll
      for (int i = 0; i < 4; ++i)
        af[i] = *(const bf16x8*)&Als[wm * 64 + i * 16 + lr][(ks * 32 + g * 8) ^ sw];
#pragma unroll
      for (int j = 0; j < 4; ++j)
        bfv[j] = *(const bf16x8*)&Bls[wn * 64 + j * 16 + lr][(ks * 32 + g * 8) ^ sw];
#pragma unroll
      for (int i = 0; i < 4; ++i)
#pragma unroll
        for (int j = 0; j < 4; ++j)
          acc[i][j] = __builtin_amdgcn_mfma_f32_16x16x32_bf16(af[i], bfv[j], acc[i][j], 0, 0, 0);
    }
    __syncthreads();
  }

  // epilogue: C/D layout col=lane&15, row=(lane>>4)*4+e
#pragma unroll
  for (int i = 0; i < 4; ++i) {
#pragma unroll
    for (int j = 0; j < 4; ++j) {
#pragma unroll
      for (int e = 0; e < 4; ++e) {
        int m = m0 + wm * 64 + i * 16 + g * 4 + e;
        int n = n0 + wn * 64 + j * 16 + lr;
        float v = acc[i][j][e] + bias[n];
        if (QKV) {
          int b = m >> 11, t = m & 2047;
          int which = n >> 10, hn = n & 1023;
          int h = hn >> 6, d = hn & 63;
          bf16_t* dst = (which == 0) ? Qb : (which == 1) ? Kb : Vb;
          dst[(((size_t)(b * 16 + h)) * 2048 + t) * 64 + d] = (bf16_t)v;
        } else {
          Out[(size_t)m * 1024 + n] = v;
        }
      }
    }
  }
}

// ---------------- flash attention, causal, hd=64 ---------------------------
// QBLK=128, KVBLK=128, 8 waves x 16 q-rows (waves 0-3: rows 0-63; 4-7: 64-127).
// Swapped QK^T (S^T = K*Q^T) -> lane-local softmax. K staged via
// global_load_lds (pre-swizzled source); V^T reg-transposed with d-key swizzle.
__global__ __launch_bounds__(512, 4) void attn_fwd(
    const bf16_t* __restrict__ Qb, const bf16_t* __restrict__ Kb,
    const bf16_t* __restrict__ Vb, bf16_t* __restrict__ Ob) {
  __shared__ bf16_t Kls[128][64];    // K tile, row-key swizzle (chunk ^= row&7)
  __shared__ bf16_t Vt[64][128];     // V^T [d][k], key = (d&7)^((d>>1)&7)
  __shared__ bf16_t Pl[8][16][128];  // per-wave P, row-key swizzle

  // XCD-aware, load-balanced: 64 blocks/XCD = 4 bh x 16 qb; blocks id and
  // id+256 (co-resident on a CU) get qb and 15-qb -> uniform 17 tiles/CU-slot.
  int id = blockIdx.x;
  int xcd = id & 7, j = id >> 3;
  int lo = j & 31, hi = j >> 5;
  int bh = xcd * 4 + (lo & 3);
  int qb = hi ? 15 - (lo >> 2) : (lo >> 2);
  int b = bh >> 4, h = bh & 15;

  const int tid = threadIdx.x, lane = tid & 63, w = tid >> 6;
  const int grp = w >> 2, wl = w & 3;
  const int g = lane >> 4, lr = lane & 15;
  const int sw = (lane & 7) << 3;
  const bf16_t* Qp = Qb + (size_t)bh * 2048 * 64;
  const bf16_t* Kp = Kb + (size_t)bh * 2048 * 64;
  const bf16_t* Vp = Vb + (size_t)bh * 2048 * 64;
  const float sc = 0.125f * LOG2E;

  const int q0 = qb * 128;
  const int qrow = q0 + grp * 64 + wl * 16 + lr;

  bf16x8 qf0, qf1;
  {
    const bf16_t* qsrc = Qp + (size_t)qrow * 64 + g * 8;
    qf0 = *(const bf16x8*)(qsrc);
    qf1 = *(const bf16x8*)(qsrc + 32);
  }

  // V^T read keys: key(d) = ((d&7) ^ ((d>>1)&7)) << 3, d = fc2*16+lr
  int vkey[4];
#pragma unroll
  for (int fc2 = 0; fc2 < 4; ++fc2) {
    int d = fc2 * 16 + lr;
    vkey[fc2] = (((d & 7) ^ ((d >> 1) & 7)) << 3);
  }

  // K staging source (pre-swizzled): lane covers row (base+lane>>3), chunk lane&7
  const int ksrow = lane >> 3;
  const int ksoff = ((lane & 7) ^ ksrow) * 8;

  float m_run = -3e38f, l_run = 0.f;
  f32x4 oacc[4] = {};
  const int ktiles = qb + 1;

  for (int kt = 0; kt < ktiles; ++kt) {
    const int k0 = kt * 128;
    const bool lastt = (kt == ktiles - 1);
    const int famax = (lastt && grp == 0) ? 4 : 8;
    __syncthreads();  // prior tile's readers done before restage

    // ---- stage K via global_load_lds: 2 calls/thread, 16 x 1KB wave-calls ----
#pragma unroll
    for (int c = 0; c < 2; ++c) {
      int rbase = (w * 2 + c) * 8;
      gll16(Kp + (size_t)(k0 + rbase + ksrow) * 64 + ksoff, &Kls[rbase][0]);
    }

    // ---- stage V^T: per-thread 8k x 2d in-register transpose via v_perm ----
    {
      int kbase = (tid >> 5) * 8;   // 0..120
      int dbase = (tid & 31) * 2;   // 0..62
      u32 rowv[8];
#pragma unroll
      for (int r = 0; r < 8; ++r)
        rowv[r] = *(const u32*)(Vp + (size_t)(k0 + kbase + r) * 64 + dbase);
#pragma unroll
      for (int dd = 0; dd < 2; ++dd) {
        u32 sel = dd ? 0x07060302u : 0x05040100u;
        int4 val;
        val.x = __builtin_amdgcn_perm(rowv[1], rowv[0], sel);
        val.y = __builtin_amdgcn_perm(rowv[3], rowv[2], sel);
        val.z = __builtin_amdgcn_perm(rowv[5], rowv[4], sel);
        val.w = __builtin_amdgcn_perm(rowv[7], rowv[6], sel);
        int d = dbase + dd;
        int key = ((d & 7) ^ ((d >> 1) & 7)) << 3;
        *(int4*)&Vt[d][kbase ^ key] = val;
      }
    }
    __syncthreads();

    // ---- QK^T (swapped): S^T fragments, lane owns q=qrow ----
    f32x4 s[8] = {};
#pragma unroll
    for (int ks = 0; ks < 2; ++ks) {
#pragma unroll
      for (int fa = 0; fa < 8; ++fa) {
        if (fa < famax) {
          bf16x8 kf = *(const bf16x8*)&Kls[fa * 16 + lr][(ks * 32 + g * 8) ^ sw];
          s[fa] = __builtin_amdgcn_mfma_f32_16x16x32_bf16(kf, ks ? qf1 : qf0, s[fa], 0, 0, 0);
        }
      }
    }

    // ---- softmax: lane-local over 32 (or 16) kk values ----
    float mloc = -3e38f;
#pragma unroll
    for (int fa = 0; fa < 8; ++fa) {
      if (fa < famax) {
#pragma unroll
        for (int e = 0; e < 4; ++e) {
          float v = s[fa][e] * sc;
          if (lastt) {
            int kk = k0 + fa * 16 + g * 4 + e;
            v = (kk > qrow) ? -3e38f : v;
          }
          s[fa][e] = v;
          mloc = fmaxf(mloc, v);
        }
      }
    }
    mloc = fmaxf(mloc, __shfl_xor(mloc, 16, 64));
    mloc = fmaxf(mloc, __shfl_xor(mloc, 32, 64));
    if (!__all(mloc <= m_run + 8.0f)) {   // defer-max (T13)
      float mnew = fmaxf(m_run, mloc);
      float rs = __builtin_amdgcn_exp2f(m_run - mnew);
      m_run = mnew;
      l_run *= rs;
      float rs_e[4];
#pragma unroll
      for (int e = 0; e < 4; ++e) rs_e[e] = __shfl(rs, g * 4 + e, 64);
#pragma unroll
      for (int fc2 = 0; fc2 < 4; ++fc2)
#pragma unroll
        for (int e = 0; e < 4; ++e) oacc[fc2][e] *= rs_e[e];
    }
    float lsum = 0.f;
#pragma unroll
    for (int fa = 0; fa < 8; ++fa) {
      if (fa < famax) {
        float p0 = __builtin_amdgcn_exp2f(s[fa][0] - m_run);
        float p1 = __builtin_amdgcn_exp2f(s[fa][1] - m_run);
        float p2 = __builtin_amdgcn_exp2f(s[fa][2] - m_run);
        float p3 = __builtin_amdgcn_exp2f(s[fa][3] - m_run);
        lsum += (p0 + p1) + (p2 + p3);
        bf16x4 pv = {(bf16_t)p0, (bf16_t)p1, (bf16_t)p2, (bf16_t)p3};
        *(bf16x4*)&Pl[w][lr][(fa * 16 + g * 4) ^ sw] = pv;
      }
    }
    lsum += __shfl_xor(lsum, 16, 64);
    lsum += __shfl_xor(lsum, 32, 64);
    l_run += lsum;

    // wave-local P visibility (Pl[w] is per-wave)
    asm volatile("s_waitcnt lgkmcnt(0)" ::: "memory");
    __builtin_amdgcn_sched_barrier(0);

    // ---- O += P @ V ----
    const int ks2max = (lastt && grp == 0) ? 2 : 4;
#pragma unroll
    for (int ks2 = 0; ks2 < 4; ++ks2) {
      if (ks2 < ks2max) {
        bf16x8 pa = *(const bf16x8*)&Pl[w][lr][(ks2 * 32 + g * 8) ^ sw];
#pragma unroll
        for (int fc2 = 0; fc2 < 4; ++fc2) {
          bf16x8 vf = *(const bf16x8*)&Vt[fc2 * 16 + lr][(ks2 * 32 + g * 8) ^ vkey[fc2]];
          oacc[fc2] = __builtin_amdgcn_mfma_f32_16x16x32_bf16(pa, vf, oacc[fc2], 0, 0, 0);
        }
      }
    }
  }  // kt

  // ---- epilogue: O[q][d], q = g*4+e, d = fc2*16+lr ----
  float le[4];
#pragma unroll
  for (int e = 0; e < 4; ++e) le[e] = __shfl(l_run, g * 4 + e, 64);
#pragma unroll
  for (int e = 0; e < 4; ++e) {
    float inv = 1.0f / le[e];
    int t = q0 + grp * 64 + wl * 16 + g * 4 + e;
#pragma unroll
    for (int fc2 = 0; fc2 < 4; ++fc2) {
      int dcol = h * 64 + fc2 * 16 + lr;
      Ob[((size_t)(b * 2048 + t)) * 1024 + dcol] = (bf16_t)(oacc[fc2][e] * inv);
    }
  }
}

// ---------------------------------------------------------------------------
extern "C" void kernel_launch(void* const* d_in, const int* in_sizes, int n_in,
                              void* d_out, int out_size, void* d_ws, size_t ws_size,
                              hipStream_t stream) {
  const float* x      = (const float*)d_in[0];
  const float* W_attn = (const float*)d_in[1];
  const float* b_attn = (const float*)d_in[2];
  const float* A_attn = (const float*)d_in[3];
  const float* B_attn = (const float*)d_in[4];
  const float* W_proj = (const float*)d_in[5];
  const float* b_proj = (const float*)d_in[6];
  const float* A_proj = (const float*)d_in[7];
  const float* B_proj = (const float*)d_in[8];
  float* out = (float*)d_out;

  char* ws = (char*)d_ws;
  bf16_t* WaE = (bf16_t*)(ws);               // 3072*1024*2
  bf16_t* WpE = (bf16_t*)(ws + 6291456);     // 1024*1024*2
  bf16_t* Xb  = (bf16_t*)(ws + 8388608);     // 4096*1024*2
  bf16_t* Qb  = (bf16_t*)(ws + 16777216);    // [B*H][T][64]
  bf16_t* Kb  = (bf16_t*)(ws + 25165824);
  bf16_t* Vb  = (bf16_t*)(ws + 33554432);
  bf16_t* Ob  = (bf16_t*)(ws + 41943040);    // [B*T][C] bf16

  prep_weff<<<12288, 256, 0, stream>>>(W_attn, B_attn, A_attn, WaE, 3072 * 1024);
  prep_weff<<<4096, 256, 0, stream>>>(W_proj, B_proj, A_proj, WpE, 1024 * 1024);
  cast_bf4<<<4096, 256, 0, stream>>>((const float4*)x, (bf16x4*)Xb, 1048576);

  gemm_bt<true><<<dim3(32, 24), 256, 0, stream>>>(Xb, WaE, b_attn, Qb, Kb, Vb, nullptr);
  attn_fwd<<<512, 512, 0, stream>>>(Qb, Kb, Vb, Ob);
  gemm_bt<false><<<dim3(32, 8), 256, 0, stream>>>(Ob, WpE, b_proj, nullptr, nullptr, nullptr, out);
}